// Round 8
// baseline (305.256 us; speedup 1.0000x reference)
//
#include <hip/hip_runtime.h>
#include <math.h>

#define Bb 2
#define Tt 4096
#define Cc 768
#define Hh 12
#define Dd 64

typedef __attribute__((ext_vector_type(8))) short short8;
typedef __attribute__((ext_vector_type(4))) float f32x4;
typedef __attribute__((ext_vector_type(16))) float f32x16;
typedef __attribute__((ext_vector_type(4))) unsigned short u16x4;

static __device__ __forceinline__ unsigned short f2bf(float f) {
    unsigned u = __float_as_uint(f);
    u += 0x7FFF + ((u >> 16) & 1);          // round-to-nearest-even
    return (unsigned short)(u >> 16);
}

static __device__ __forceinline__ float ex2(float x) {
    return __builtin_amdgcn_exp2f(x);
}

static __device__ __forceinline__ void gload16(const void* g, void* l) {
    __builtin_amdgcn_global_load_lds(
        (const __attribute__((address_space(1))) unsigned*)g,
        (__attribute__((address_space(3))) unsigned*)l, 16, 0, 0);
}

// ---------------------------------------------------------------------------
// fp32 -> bf16 elementwise convert (8 elems/thread)
// ---------------------------------------------------------------------------
__global__ __launch_bounds__(256)
void cvt_bf16(const float* __restrict__ in, unsigned short* __restrict__ out, int n8) {
    int i = blockIdx.x * 256 + threadIdx.x;
    if (i >= n8) return;
    float4 a = *(const float4*)(in + (size_t)i * 8);
    float4 b = *(const float4*)(in + (size_t)i * 8 + 4);
    union { short8 v; unsigned short u[8]; } p;
    p.u[0] = f2bf(a.x); p.u[1] = f2bf(a.y); p.u[2] = f2bf(a.z); p.u[3] = f2bf(a.w);
    p.u[4] = f2bf(b.x); p.u[5] = f2bf(b.y); p.u[6] = f2bf(b.z); p.u[7] = f2bf(b.w);
    *(short8*)(out + (size_t)i * 8) = p.v;
}

// ---------------------------------------------------------------------------
// W[K][N] fp32 -> Wt[N][K] bf16 (64x64 LDS tile transpose)
// ---------------------------------------------------------------------------
__global__ __launch_bounds__(256)
void transpose_w(const float* __restrict__ W, unsigned short* __restrict__ Wt,
                 int K, int N) {
    __shared__ __align__(16) unsigned short Tl[64][72];
    int n0 = blockIdx.x * 64, k0 = blockIdx.y * 64;
    int t = threadIdx.x;
    int r = t >> 2, c = (t & 3) * 16;
    const float* wp = W + (size_t)(k0 + r) * N + n0 + c;
    #pragma unroll
    for (int j = 0; j < 16; j += 4) {
        float4 v = *(const float4*)(wp + j);
        Tl[c + j + 0][r] = f2bf(v.x);
        Tl[c + j + 1][r] = f2bf(v.y);
        Tl[c + j + 2][r] = f2bf(v.z);
        Tl[c + j + 3][r] = f2bf(v.w);
    }
    __syncthreads();
    unsigned short* op = Wt + (size_t)(n0 + r) * K + k0 + c;
    *(short8*)op       = *(const short8*)&Tl[r][c];
    *(short8*)(op + 8) = *(const short8*)&Tl[r][c + 8];
}

// ---------------------------------------------------------------------------
// V slice of bf16 qkv -> Vt[b][h][d][t]  (64x64 LDS tile transpose)
// ---------------------------------------------------------------------------
__global__ __launch_bounds__(256)
void repack_vt(const unsigned short* __restrict__ qkvb, unsigned short* __restrict__ vtb) {
    __shared__ __align__(16) unsigned short Tl[64][72];
    int t0 = blockIdx.x * 64, h = blockIdx.y, b = blockIdx.z;
    int t = threadIdx.x;
    int r = t >> 2, c = (t & 3) * 16;
    const unsigned short* vp = qkvb + (size_t)((size_t)b * Tt + t0 + r) * (3 * Cc)
                               + 2 * Cc + h * Dd + c;
    short8 v0 = *(const short8*)vp;
    short8 v1 = *(const short8*)(vp + 8);
    #pragma unroll
    for (int j = 0; j < 8; ++j) {
        Tl[c + j][r]     = ((unsigned short*)&v0)[j];
        Tl[c + 8 + j][r] = ((unsigned short*)&v1)[j];
    }
    __syncthreads();
    unsigned short* op = vtb + ((size_t)((b * Hh + h) * Dd) + r) * Tt + t0 + c;
    *(short8*)op       = *(const short8*)&Tl[r][c];
    *(short8*)(op + 8) = *(const short8*)&Tl[r][c + 8];
}

// ---------------------------------------------------------------------------
// bf16 MFMA GEMM: C[M,N] = (A[M,K] @ Bt[N,K]^T + bias) * (col<qcols ? qscale : 1)
// 128x128 tile, BK=64, 256 threads (4 waves, 2x2), global_load_lds staging.
// ---------------------------------------------------------------------------
template<bool BF16OUT>
__global__ __launch_bounds__(256)
void gemm_mfma(const unsigned short* __restrict__ A, const unsigned short* __restrict__ Bt,
               const float* __restrict__ bias, void* __restrict__ Cout,
               int M, int N, int K, int qcols) {
    __shared__ __align__(16) unsigned short As[128][64];
    __shared__ __align__(16) unsigned short Bs[128][64];
    const int tid = threadIdx.x;
    const int wid = tid >> 6, lane = tid & 63;
    const int lr = lane & 15, g = lane >> 4;
    const int wr = wid >> 1, wc = wid & 1;
    const int m0 = blockIdx.y * 128, n0 = blockIdx.x * 128;
    const int srow = lane >> 3;
    const int scol = (lane & 7) * 8;

    f32x4 acc[4][4] = {};

    for (int k0 = 0; k0 < K; k0 += 64) {
        #pragma unroll
        for (int j = 0; j < 4; ++j) {
            int ci = wid * 4 + j;
            int row = ci * 8 + srow;
            gload16(A  + (size_t)(m0 + row) * K + k0 + scol, &As[ci * 8][0]);
            gload16(Bt + (size_t)(n0 + row) * K + k0 + scol, &Bs[ci * 8][0]);
        }
        __syncthreads();
        #pragma unroll
        for (int ks = 0; ks < 2; ++ks) {
            short8 af[4], bfr[4];
            #pragma unroll
            for (int m = 0; m < 4; ++m)
                af[m] = *(const short8*)&As[wr * 64 + m * 16 + lr][ks * 32 + g * 8];
            #pragma unroll
            for (int n = 0; n < 4; ++n)
                bfr[n] = *(const short8*)&Bs[wc * 64 + n * 16 + lr][ks * 32 + g * 8];
            #pragma unroll
            for (int m = 0; m < 4; ++m)
                #pragma unroll
                for (int n = 0; n < 4; ++n)
                    acc[m][n] = __builtin_amdgcn_mfma_f32_16x16x32_bf16(
                        af[m], bfr[n], acc[m][n], 0, 0, 0);
        }
        __syncthreads();
    }

    // qscale = 0.125 * log2(e): QK^T scores land directly in log2 domain.
    const float qscale = 0.125f * 1.44269504088896340736f;
    #pragma unroll
    for (int n = 0; n < 4; ++n) {
        int coln = n0 + wc * 64 + n * 16 + lr;
        float bv = bias[coln];
        float sc = (coln < qcols) ? qscale : 1.0f;
        #pragma unroll
        for (int m = 0; m < 4; ++m) {
            int rowb = m0 + wr * 64 + m * 16 + g * 4;
            #pragma unroll
            for (int r = 0; r < 4; ++r) {
                float v = (acc[m][n][r] + bv) * sc;
                if (BF16OUT)
                    ((unsigned short*)Cout)[(size_t)(rowb + r) * N + coln] = f2bf(v);
                else
                    ((float*)Cout)[(size_t)(rowb + r) * N + coln] = v;
            }
        }
    }
}

// ---------------------------------------------------------------------------
// Flash attention, 32x32x16 MFMA, swapped QK^T (S^T = K·Q^T), in-register
// softmax (log2 domain, defer-max), shfl_xor(32) P-relayout, XOR-swizzled
// dbuf K/V^T staging via global_load_lds.
// 256 threads = 4 waves; wave owns 32 q-rows; block owns 128 q of one (b,h).
//
// 32x32x16 layouts: A row=l&31, k=(l>>5)*8+j; B col=l&31, k=(l>>5)*8+j;
// C/D col=l&31, row=(reg&3)+8*(reg>>2)+4*(l>>5)  [m74/m101-verified].
// ---------------------------------------------------------------------------
__global__ __launch_bounds__(256)
void attn_mfma(const unsigned short* __restrict__ qkvb,
               const unsigned short* __restrict__ vtb,
               unsigned short* __restrict__ outb) {
    const int qb = (int)(gridDim.x - 1) - blockIdx.x;   // longest-first
    const int hd = blockIdx.y, b = blockIdx.z;
    const int tid = threadIdx.x;
    const int wid = tid >> 6, lane = tid & 63;
    const int l31 = lane & 31, h = lane >> 5, l7 = lane & 7;
    const int q0 = qb * 128;
    const size_t rs = 3 * Cc;

    __shared__ __align__(16) unsigned short Ks[2][64 * 64];   // K  [key][d], swizzled
    __shared__ __align__(16) unsigned short Vs[2][64 * 64];   // V^T [d][key], swizzled

    const unsigned short* qkvbase = qkvb + (size_t)b * Tt * rs;
    const unsigned short* vbase   = vtb + (size_t)((b * Hh + hd) * Dd) * Tt;
    const int myq = q0 + wid * 32 + l31;

    // Q B-frags (0.125*log2e folded in by QKV GEMM): qf[ds] = Q[myq][ds*16+h*8 ..+7]
    short8 qf[4];
    {
        const unsigned short* qp = qkvbase + (size_t)myq * rs + hd * Dd + h * 8;
        #pragma unroll
        for (int ds = 0; ds < 4; ++ds) qf[ds] = *(const short8*)(qp + ds * 16);
    }

    // staging: lane covers row wid*8+(lane>>3) (+j*32), phys 16B-slot lane&7,
    // whose content is logical slot (lane&7)^(row&7)   (XOR involution)
    const int srw = lane >> 3;
    const int slog = l7 ^ srw;
    const unsigned short* kstage = qkvbase + (size_t)(wid * 8 + srw) * rs + Cc + hd * Dd + slog * 8;
    const unsigned short* vstage = vbase + (size_t)(wid * 8 + srw) * Tt + slog * 8;

    f32x16 o0, o1;
    #pragma unroll
    for (int i = 0; i < 16; ++i) { o0[i] = 0.f; o1[i] = 0.f; }
    float m_r = -1e30f, l_r = 0.f;

    const int ntiles = 2 * qb + 2;

    auto stage = [&](int buf, int t) {
        #pragma unroll
        for (int j = 0; j < 2; ++j) {
            gload16(kstage + ((size_t)t * 64 + j * 32) * rs, &Ks[buf][(j * 32 + wid * 8) * 64]);
            gload16(vstage + (size_t)j * 32 * Tt + t * 64,   &Vs[buf][(j * 32 + wid * 8) * 64]);
        }
    };

    stage(0, 0);
    __syncthreads();
    int cur = 0;

    for (int kbt = 0; kbt < ntiles; ++kbt) {
        if (kbt + 1 < ntiles) stage(cur ^ 1, kbt + 1);

        if (kbt * 64 <= q0 + wid * 32 + 31) {
            const unsigned short* Kc = &Ks[cur][0];
            const unsigned short* Vc = &Vs[cur][0];

            // ---- S^T = K Q^T: two 32-key blocks, accumulate over 4 d-segs ----
            f32x16 st0, st1;
            #pragma unroll
            for (int i = 0; i < 16; ++i) { st0[i] = 0.f; st1[i] = 0.f; }
            __builtin_amdgcn_s_setprio(1);
            #pragma unroll
            for (int ds = 0; ds < 4; ++ds) {
                const int p8 = ((((ds << 1) | h)) ^ l7) * 8;
                short8 k0 = *(const short8*)&Kc[l31 * 64 + p8];
                short8 k1 = *(const short8*)&Kc[(32 + l31) * 64 + p8];
                st0 = __builtin_amdgcn_mfma_f32_32x32x16_bf16(k0, qf[ds], st0, 0, 0, 0);
                st1 = __builtin_amdgcn_mfma_f32_32x32x16_bf16(k1, qf[ds], st1, 0, 0, 0);
            }
            __builtin_amdgcn_s_setprio(0);

            // ---- causal mask (diagonal band only) ----
            if (kbt * 64 + 63 > q0 + wid * 32) {
                const int kb0 = kbt * 64 + 4 * h;
                #pragma unroll
                for (int i = 0; i < 16; ++i) {
                    const int rc = (i & 3) + 8 * (i >> 2);
                    if (kb0 + rc > myq)      st0[i] = -1e30f;
                    if (kb0 + 32 + rc > myq) st1[i] = -1e30f;
                }
            }

            // ---- online softmax (lane-scalar state; halves meet via shfl) ----
            float tmax = -1e30f;
            #pragma unroll
            for (int i = 0; i < 16; ++i) tmax = fmaxf(tmax, fmaxf(st0[i], st1[i]));
            tmax = fmaxf(tmax, __shfl_xor(tmax, 32));
            if (!__all(tmax - m_r <= 8.0f)) {
                float mnew = fmaxf(m_r, tmax);
                float corr = ex2(m_r - mnew);
                l_r *= corr;
                #pragma unroll
                for (int i = 0; i < 16; ++i) { o0[i] *= corr; o1[i] *= corr; }
                m_r = mnew;
            }
            float psum = 0.f;
            #pragma unroll
            for (int i = 0; i < 16; ++i) { st0[i] = ex2(st0[i] - m_r); psum += st0[i]; }
            #pragma unroll
            for (int i = 0; i < 16; ++i) { st1[i] = ex2(st1[i] - m_r); psum += st1[i]; }
            psum += __shfl_xor(psum, 32);
            l_r += psum;

            // ---- P^T -> PV B-frags: cvt_pk pairs + cross-half shfl ----
            unsigned pw0[8], pw1[8];
            #pragma unroll
            for (int i2 = 0; i2 < 8; ++i2) {
                asm("v_cvt_pk_bf16_f32 %0, %1, %2"
                    : "=v"(pw0[i2]) : "v"(st0[2 * i2]), "v"(st0[2 * i2 + 1]));
                asm("v_cvt_pk_bf16_f32 %0, %1, %2"
                    : "=v"(pw1[i2]) : "v"(st1[2 * i2]), "v"(st1[2 * i2 + 1]));
            }
            #pragma unroll
            for (int ks = 0; ks < 4; ++ks) {
                const int c = (ks & 1) * 4;
                unsigned s0 = (ks < 2) ? pw0[c + 0] : pw1[c + 0];
                unsigned s1 = (ks < 2) ? pw0[c + 1] : pw1[c + 1];
                unsigned s2 = (ks < 2) ? pw0[c + 2] : pw1[c + 2];
                unsigned s3 = (ks < 2) ? pw0[c + 3] : pw1[c + 3];
                unsigned t0 = __shfl_xor(s2, 32);   // partner's s2 (h=1 word0/1)
                unsigned t1 = __shfl_xor(s3, 32);
                unsigned t2 = __shfl_xor(s0, 32);   // partner's s0 (h=0 word2/3)
                unsigned t3 = __shfl_xor(s1, 32);
                union { unsigned u[4]; short8 v; } pb;
                pb.u[0] = h ? t0 : s0;
                pb.u[1] = h ? t1 : s1;
                pb.u[2] = h ? s2 : t2;
                pb.u[3] = h ? s3 : t3;
                const int p8 = ((((ks << 1) | h)) ^ l7) * 8;
                __builtin_amdgcn_s_setprio(1);
                short8 v0 = *(const short8*)&Vc[l31 * 64 + p8];
                short8 v1 = *(const short8*)&Vc[(32 + l31) * 64 + p8];
                o0 = __builtin_amdgcn_mfma_f32_32x32x16_bf16(v0, pb.v, o0, 0, 0, 0);
                o1 = __builtin_amdgcn_mfma_f32_32x32x16_bf16(v1, pb.v, o1, 0, 0, 0);
                __builtin_amdgcn_s_setprio(0);
            }
        }
        __syncthreads();
        cur ^= 1;
    }

    // ---- epilogue: lane owns col q = myq; reg i of o{0,1} is d-row
    //      (i&3)+8*(i>>2)+4h (+32 for o1) ----
    float inv = 1.f / fmaxf(l_r, 1e-37f);
    unsigned short* op = outb + ((size_t)b * Tt + myq) * Cc + hd * Dd + 4 * h;
    #pragma unroll
    for (int gi = 0; gi < 4; ++gi) {
        u16x4 wv0, wv1;
        #pragma unroll
        for (int r = 0; r < 4; ++r) {
            wv0[r] = f2bf(o0[gi * 4 + r] * inv);
            wv1[r] = f2bf(o1[gi * 4 + r] * inv);
        }
        *(u16x4*)(op + gi * 8)      = wv0;
        *(u16x4*)(op + 32 + gi * 8) = wv1;
    }
}

// ---------------------------------------------------------------------------
extern "C" void kernel_launch(void* const* d_in, const int* in_sizes, int n_in,
                              void* d_out, int out_size, void* d_ws, size_t ws_size,
                              hipStream_t stream) {
    const float* x    = (const float*)d_in[0];
    const float* Wqkv = (const float*)d_in[1];
    const float* bqkv = (const float*)d_in[2];
    const float* Wout = (const float*)d_in[3];
    const float* bout = (const float*)d_in[4];
    float* out = (float*)d_out;

    const int M = Bb * Tt;          // 8192
    const int N1 = 3 * Cc;          // 2304

    char* p = (char*)d_ws;
    unsigned short* qkvb  = (unsigned short*)p; p += (size_t)M * N1 * 2;
    unsigned short* xb    = (unsigned short*)p; p += (size_t)M * Cc * 2;
    unsigned short* wqkvt = (unsigned short*)p; p += (size_t)N1 * Cc * 2;
    unsigned short* woutt = (unsigned short*)p; p += (size_t)Cc * Cc * 2;
    unsigned short* vtb   = (unsigned short*)p; p += (size_t)Bb * Hh * Dd * Tt * 2;
    unsigned short* attb  = (unsigned short*)p; p += (size_t)M * Cc * 2;

    cvt_bf16<<<dim3((M * Cc / 8 + 255) / 256), dim3(256), 0, stream>>>(x, xb, M * Cc / 8);
    transpose_w<<<dim3(N1 / 64, Cc / 64), dim3(256), 0, stream>>>(Wqkv, wqkvt, Cc, N1);
    transpose_w<<<dim3(Cc / 64, Cc / 64), dim3(256), 0, stream>>>(Wout, woutt, Cc, Cc);

    // qkv = x @ Wqkv + bqkv, Q columns pre-scaled by 0.125*log2(e) (bf16 out)
    gemm_mfma<true><<<dim3(N1 / 128, M / 128), dim3(256), 0, stream>>>(
        xb, wqkvt, bqkv, qkvb, M, N1, Cc, Cc);

    repack_vt<<<dim3(Tt / 64, Hh, Bb), dim3(256), 0, stream>>>(qkvb, vtb);

    attn_mfma<<<dim3(Tt / 128, Hh, Bb), dim3(256), 0, stream>>>(qkvb, vtb, attb);

    gemm_mfma<false><<<dim3(Cc / 128, M / 128), dim3(256), 0, stream>>>(
        attb, woutt, bout, out, M, Cc, Cc, 0);
}